// Round 8
// baseline (89.472 us; speedup 1.0000x reference)
//
#include <hip/hip_runtime.h>
#include <hip/hip_bf16.h>
#include <hip/hip_fp16.h>
#include <string.h>

#define NL 32
#define HID 64

// Piecewise-linear table over z1 in [-16, 16], 2048 cells (width 1/64).
// ReLU MLP on a scalar is exactly piecewise-linear; lerp + edge extrapolation
// validated rounds 1-6 (absmax 0.031 vs threshold 0.209).
// Cell entry packed as 4 x fp16 = 8 B: half2(shift, scale) + half2(dshift,
// dscale). Gather is ds_read_b64 (half the LDS phases of b128), lerp is one
// v_pk_fma_f16. Table: 16 KB/layer -> 32 KB double-buffer -> 4 blocks/CU.
#define NCELLS 2048
#define NNODES (NCELLS + 1)
#define SCALE  64.0f
#define OFFSET 1024.0f
#define TAB_BYTES ((size_t)NL * NCELLS * sizeof(uint2))   // 512 KB

#define BN  256                      // cells per build block
#define TPB 512                      // 8 waves per block
#define RPT 4                        // rows per thread -> 1024 blocks = 4/CU
#define ROWS_PER_BLOCK (TPB * RPT)   // 2048

// ------------- fused build: eval 257 nodes, write 256 packed cells ---------
// blockIdx.y = layer -> weight reads wave-uniform. Threads 0..256 (of 320)
// each eval the exact fp32 MLP at one node; LDS exchange gives the neighbor
// node for the slope; threads 0..255 write the packed fp16 cell entry.
__global__ __launch_bounds__(320) void build_cells_kernel(
    const float* __restrict__ W1,
    const float* __restrict__ b1,
    const float* __restrict__ W2,
    const float* __restrict__ b2,
    const float* __restrict__ W3,
    const float* __restrict__ b3,
    uint2* __restrict__ tab)
{
    const int tid = threadIdx.x;
    const int l = blockIdx.y;
    const int base = blockIdx.x * BN;

    __shared__ float2 nodes[BN + 1];

    if (tid <= BN) {
        int node = base + tid;
        float a = -16.0f + (float)node * (1.0f / 64.0f);   // exact in fp32

        const float* __restrict__ w1 = W1 + l * HID;
        const float* __restrict__ c1 = b1 + l * HID;
        const float* __restrict__ w2 = W2 + l * HID * HID;
        const float* __restrict__ c2 = b2 + l * HID;
        const float* __restrict__ w3 = W3 + l * 2 * HID;
        const float* __restrict__ c3 = b3 + l * 2;

        float h1[HID];
        #pragma unroll
        for (int k = 0; k < HID; ++k) {
            float v = fmaxf(fmaf(a, w1[k], c1[k]), 0.0f);
            asm volatile("" : "+v"(v));   // pin in VGPR; block remat
            h1[k] = v;
        }

        float o0 = c3[0];
        float o1 = c3[1];

        #pragma unroll 2
        for (int j = 0; j < HID; ++j) {
            const float* __restrict__ w2row = w2 + j * HID;
            float acc0 = c2[j];
            float acc1 = 0.0f;
            #pragma unroll
            for (int k = 0; k < HID; k += 2) {
                acc0 = fmaf(h1[k],     w2row[k],     acc0);
                acc1 = fmaf(h1[k + 1], w2row[k + 1], acc1);
            }
            float h = fmaxf(acc0 + acc1, 0.0f);
            o0 = fmaf(h, w3[j], o0);
            o1 = fmaf(h, w3[HID + j], o1);
        }

        nodes[tid] = make_float2(o0, expf(o1));  // (shift, scale)
    }
    __syncthreads();

    if (tid < BN) {
        float2 v0 = nodes[tid];
        float2 v1 = nodes[tid + 1];
        __half2 bh = __halves2half2(__float2half_rn(v0.x),
                                    __float2half_rn(v0.y));
        __half2 dh = __halves2half2(__float2half_rn(v1.x - v0.x),
                                    __float2half_rn(v1.y - v0.y));
        uint2 e;
        memcpy(&e.x, &bh, 4);
        memcpy(&e.y, &dh, 4);
        tab[(size_t)l * NCELLS + base + tid] = e;
    }
}

// ---------------- helpers ---------------------------------------------------
__device__ __forceinline__ float2 nt_load_f2(const float* p) {
    unsigned long long raw =
        __builtin_nontemporal_load((const unsigned long long*)p);
    float2 v;
    memcpy(&v, &raw, 8);
    return v;
}
__device__ __forceinline__ void nt_store_f2(float* p, float2 v) {
    unsigned long long raw;
    memcpy(&raw, &v, 8);
    __builtin_nontemporal_store(raw, (unsigned long long*)p);
}

// ---------------- main pass: fp16 LDS cell table, dbuf, 4 blocks/CU --------
__global__ __launch_bounds__(TPB, 8) void flow_lds_kernel(
    const float* __restrict__ x,
    const uint2* __restrict__ tabg,
    float* __restrict__ out,
    int nrows)
{
    __shared__ float4 buf4[2][NCELLS / 2];   // 2 x 16 KiB

    const int tid = threadIdx.x;
    const size_t rbase = (size_t)blockIdx.x * ROWS_PER_BLOCK;

    float a[RPT], b[RPT];
    #pragma unroll
    for (int i = 0; i < RPT; ++i) {
        size_t r = rbase + (size_t)i * TPB + tid;
        float2 z = (r < (size_t)nrows) ? nt_load_f2(x + 2 * r)
                                       : make_float2(0.f, 0.f);
        a[i] = z.x;
        b[i] = z.y;
    }

    // stage layer 0 into buf4[0]
    {
        const float4* __restrict__ src = (const float4*)tabg;
        buf4[0][tid]       = src[tid];
        buf4[0][tid + TPB] = src[tid + TPB];
    }
    __syncthreads();

    int cur = 0;
    for (int l = 0; l < NL; ++l) {
        // issue next-layer staging loads into registers (no wait yet)
        float4 s0, s1;
        if (l + 1 < NL) {
            const float4* __restrict__ src =
                (const float4*)(tabg + (size_t)(l + 1) * NCELLS);
            s0 = src[tid];
            s1 = src[tid + TPB];
        }

        // gather-compute current layer from buf4[cur]
        const uint2* __restrict__ B = (const uint2*)buf4[cur];
        #pragma unroll
        for (int i = 0; i < RPT; ++i) {
            float t = fmaf(a[i], SCALE, OFFSET);
            int idx = (int)t;
            idx = idx < 0 ? 0 : (idx > NCELLS - 1 ? NCELLS - 1 : idx);
            float f = t - (float)idx;            // out-of-range -> extrapolate
            f = fminf(fmaxf(f, -8192.0f), 8192.0f);
            uint2 e = B[idx];
            __half2 bh, dh;
            memcpy(&bh, &e.x, 4);
            memcpy(&dh, &e.y, 4);
            __half2 r = __hfma2(__float2half2_rn(f), dh, bh);
            float sh = __low2float(r);
            float sc = __high2float(r);
            float nb = fmaf(b[i], sc, sh);
            b[i] = a[i];
            a[i] = nb;
        }

        // write staged regs to the other half
        if (l + 1 < NL) {
            buf4[cur ^ 1][tid]       = s0;
            buf4[cur ^ 1][tid + TPB] = s1;
        }
        __syncthreads();
        cur ^= 1;
    }

    #pragma unroll
    for (int i = 0; i < RPT; ++i) {
        size_t r = rbase + (size_t)i * TPB + tid;
        if (r < (size_t)nrows)
            nt_store_f2(out + 2 * r, make_float2(a[i], b[i]));
    }
}

// ---------------- fallback: direct fp32 (ws too small) ---------------------
__global__ __launch_bounds__(256, 2) void flow_fp32_kernel(
    const float* __restrict__ x,
    const float* __restrict__ W1,
    const float* __restrict__ b1,
    const float* __restrict__ W2,
    const float* __restrict__ b2,
    const float* __restrict__ W3,
    const float* __restrict__ b3,
    float* __restrict__ out,
    int nrows)
{
    int row = blockIdx.x * blockDim.x + threadIdx.x;
    if (row >= nrows) return;

    float2 z = reinterpret_cast<const float2*>(x)[row];
    float a = z.x;
    float b = z.y;

    for (int l = 0; l < NL; ++l) {
        const float* __restrict__ w1 = W1 + l * HID;
        const float* __restrict__ c1 = b1 + l * HID;
        const float* __restrict__ w2 = W2 + l * HID * HID;
        const float* __restrict__ c2 = b2 + l * HID;
        const float* __restrict__ w3 = W3 + l * 2 * HID;
        const float* __restrict__ c3 = b3 + l * 2;

        float h1[HID];
        #pragma unroll
        for (int k = 0; k < HID; ++k) {
            float v = fmaxf(fmaf(a, w1[k], c1[k]), 0.0f);
            asm volatile("" : "+v"(v));
            h1[k] = v;
        }

        float o0 = c3[0];
        float o1 = c3[1];

        #pragma unroll 2
        for (int j = 0; j < HID; ++j) {
            const float* __restrict__ w2row = w2 + j * HID;
            float acc0 = c2[j];
            float acc1 = 0.0f;
            #pragma unroll
            for (int k = 0; k < HID; k += 2) {
                acc0 = fmaf(h1[k],     w2row[k],     acc0);
                acc1 = fmaf(h1[k + 1], w2row[k + 1], acc1);
            }
            float h = fmaxf(acc0 + acc1, 0.0f);
            o0 = fmaf(h, w3[j], o0);
            o1 = fmaf(h, w3[HID + j], o1);
        }

        float nb = fmaf(b, __expf(o1), o0);
        b = a;
        a = nb;
    }

    reinterpret_cast<float2*>(out)[row] = make_float2(a, b);
}

extern "C" void kernel_launch(void* const* d_in, const int* in_sizes, int n_in,
                              void* d_out, int out_size, void* d_ws, size_t ws_size,
                              hipStream_t stream)
{
    const float* x  = (const float*)d_in[0];
    const float* W1 = (const float*)d_in[1];
    const float* b1 = (const float*)d_in[2];
    const float* W2 = (const float*)d_in[3];
    const float* b2 = (const float*)d_in[4];
    const float* W3 = (const float*)d_in[5];
    const float* b3 = (const float*)d_in[6];
    float* out = (float*)d_out;

    int nrows = in_sizes[0] / 2;

    if (ws_size >= TAB_BYTES) {
        uint2* tab = (uint2*)d_ws;
        dim3 bgrid(NCELLS / BN, NL);
        build_cells_kernel<<<bgrid, 320, 0, stream>>>(W1, b1, W2, b2, W3, b3, tab);
        int grid = (nrows + ROWS_PER_BLOCK - 1) / ROWS_PER_BLOCK;
        flow_lds_kernel<<<grid, TPB, 0, stream>>>(x, tab, out, nrows);
    } else {
        int grid = (nrows + 255) / 256;
        flow_fp32_kernel<<<grid, 256, 0, stream>>>(x, W1, b1, W2, b2, W3, b3, out, nrows);
    }
}

// Round 9
// 87.041 us; speedup vs baseline: 1.0279x; 1.0279x over previous
//
#include <hip/hip_runtime.h>
#include <hip/hip_bf16.h>
#include <hip/hip_fp16.h>
#include <string.h>

#define NL 32
#define HID 64

// Piecewise-linear table over z1 in [-16, 16], 2048 cells (width 1/64).
// ReLU MLP on a scalar is exactly piecewise-linear; lerp + edge extrapolation
// validated rounds 1-7. Cell entry packed as 4 x fp16 = 8 B:
// half2(shift, scale) + half2(dshift, dscale). Gather is ds_read_b64.
#define NCELLS 2048
#define NNODES (NCELLS + 1)
#define SCALE  64.0f
#define OFFSET 1024.0f
#define TAB_BYTES ((size_t)NL * NCELLS * sizeof(uint2))   // 512 KB

#define BN  256                      // cells per build block
#define TPB 512                      // 8 waves per block
#define RPT 8                        // rows per thread -> 512 blocks = 2/CU
#define ROWS_PER_BLOCK (TPB * RPT)   // 4096

// ------------- fused build: eval 257 nodes, write 256 packed cells ---------
__global__ __launch_bounds__(320) void build_cells_kernel(
    const float* __restrict__ W1,
    const float* __restrict__ b1,
    const float* __restrict__ W2,
    const float* __restrict__ b2,
    const float* __restrict__ W3,
    const float* __restrict__ b3,
    uint2* __restrict__ tab)
{
    const int tid = threadIdx.x;
    const int l = blockIdx.y;
    const int base = blockIdx.x * BN;

    __shared__ float2 nodes[BN + 1];

    if (tid <= BN) {
        int node = base + tid;
        float a = -16.0f + (float)node * (1.0f / 64.0f);   // exact in fp32

        const float* __restrict__ w1 = W1 + l * HID;
        const float* __restrict__ c1 = b1 + l * HID;
        const float* __restrict__ w2 = W2 + l * HID * HID;
        const float* __restrict__ c2 = b2 + l * HID;
        const float* __restrict__ w3 = W3 + l * 2 * HID;
        const float* __restrict__ c3 = b3 + l * 2;

        float h1[HID];
        #pragma unroll
        for (int k = 0; k < HID; ++k) {
            float v = fmaxf(fmaf(a, w1[k], c1[k]), 0.0f);
            asm volatile("" : "+v"(v));   // pin in VGPR; block remat
            h1[k] = v;
        }

        float o0 = c3[0];
        float o1 = c3[1];

        #pragma unroll 2
        for (int j = 0; j < HID; ++j) {
            const float* __restrict__ w2row = w2 + j * HID;
            float acc0 = c2[j];
            float acc1 = 0.0f;
            #pragma unroll
            for (int k = 0; k < HID; k += 2) {
                acc0 = fmaf(h1[k],     w2row[k],     acc0);
                acc1 = fmaf(h1[k + 1], w2row[k + 1], acc1);
            }
            float h = fmaxf(acc0 + acc1, 0.0f);
            o0 = fmaf(h, w3[j], o0);
            o1 = fmaf(h, w3[HID + j], o1);
        }

        nodes[tid] = make_float2(o0, expf(o1));  // (shift, scale)
    }
    __syncthreads();

    if (tid < BN) {
        float2 v0 = nodes[tid];
        float2 v1 = nodes[tid + 1];
        __half2 bh = __halves2half2(__float2half_rn(v0.x),
                                    __float2half_rn(v0.y));
        __half2 dh = __halves2half2(__float2half_rn(v1.x - v0.x),
                                    __float2half_rn(v1.y - v0.y));
        uint2 e;
        memcpy(&e.x, &bh, 4);
        memcpy(&e.y, &dh, 4);
        tab[(size_t)l * NCELLS + base + tid] = e;
    }
}

// ---------------- helpers ---------------------------------------------------
__device__ __forceinline__ float2 nt_load_f2(const float* p) {
    unsigned long long raw =
        __builtin_nontemporal_load((const unsigned long long*)p);
    float2 v;
    memcpy(&v, &raw, 8);
    return v;
}
__device__ __forceinline__ void nt_store_f2(float* p, float2 v) {
    unsigned long long raw;
    memcpy(&raw, &v, 8);
    __builtin_nontemporal_store(raw, (unsigned long long*)p);
}

// ---------------- main pass: fp16 LDS table, dbuf, RPT=8, 2 blocks/CU ------
// Round-6 structure + 8B entries. Staged registers are PINNED with an asm
// barrier right after the loads: prevents the compiler from sinking the
// global loads past the gather phase (round-7 pathology, VGPR=20), so L2
// latency hides under the gather compute.
__global__ __launch_bounds__(TPB) void flow_lds_kernel(
    const float* __restrict__ x,
    const uint2* __restrict__ tabg,
    float* __restrict__ out,
    int nrows)
{
    __shared__ uint2 buf[2][NCELLS];   // 2 x 16 KiB

    const int tid = threadIdx.x;
    const size_t rbase = (size_t)blockIdx.x * ROWS_PER_BLOCK;

    float a[RPT], b[RPT];
    #pragma unroll
    for (int i = 0; i < RPT; ++i) {
        size_t r = rbase + (size_t)i * TPB + tid;
        float2 z = (r < (size_t)nrows) ? nt_load_f2(x + 2 * r)
                                       : make_float2(0.f, 0.f);
        a[i] = z.x;
        b[i] = z.y;
    }

    // stage layer 0 into buf[0]
    {
        const float4* __restrict__ src = (const float4*)tabg;
        ((float4*)buf[0])[tid]       = src[tid];
        ((float4*)buf[0])[tid + TPB] = src[tid + TPB];
    }
    __syncthreads();

    int cur = 0;
    for (int l = 0; l < NL; ++l) {
        // issue next-layer staging loads; pin so they can't be sunk
        float4 s0, s1;
        if (l + 1 < NL) {
            const float4* __restrict__ src =
                (const float4*)(tabg + (size_t)(l + 1) * NCELLS);
            s0 = src[tid];
            s1 = src[tid + TPB];
            asm volatile("" : "+v"(s0.x), "+v"(s0.y), "+v"(s0.z), "+v"(s0.w),
                              "+v"(s1.x), "+v"(s1.y), "+v"(s1.z), "+v"(s1.w));
        }

        // gather-compute current layer from buf[cur]
        #pragma unroll
        for (int i = 0; i < RPT; ++i) {
            float t = fmaf(a[i], SCALE, OFFSET);
            int idx = (int)t;
            idx = idx < 0 ? 0 : (idx > NCELLS - 1 ? NCELLS - 1 : idx);
            float f = t - (float)idx;            // out-of-range -> extrapolate
            f = fminf(fmaxf(f, -8192.0f), 8192.0f);
            uint2 e = buf[cur][idx];
            __half2 bh, dh;
            memcpy(&bh, &e.x, 4);
            memcpy(&dh, &e.y, 4);
            __half2 r = __hfma2(__float2half2_rn(f), dh, bh);
            float sh = __low2float(r);
            float sc = __high2float(r);
            float nb = fmaf(b[i], sc, sh);
            b[i] = a[i];
            a[i] = nb;
        }

        // write staged regs to the other half
        if (l + 1 < NL) {
            ((float4*)buf[cur ^ 1])[tid]       = s0;
            ((float4*)buf[cur ^ 1])[tid + TPB] = s1;
        }
        __syncthreads();
        cur ^= 1;
    }

    #pragma unroll
    for (int i = 0; i < RPT; ++i) {
        size_t r = rbase + (size_t)i * TPB + tid;
        if (r < (size_t)nrows)
            nt_store_f2(out + 2 * r, make_float2(a[i], b[i]));
    }
}

// ---------------- fallback: direct fp32 (ws too small) ---------------------
__global__ __launch_bounds__(256, 2) void flow_fp32_kernel(
    const float* __restrict__ x,
    const float* __restrict__ W1,
    const float* __restrict__ b1,
    const float* __restrict__ W2,
    const float* __restrict__ b2,
    const float* __restrict__ W3,
    const float* __restrict__ b3,
    float* __restrict__ out,
    int nrows)
{
    int row = blockIdx.x * blockDim.x + threadIdx.x;
    if (row >= nrows) return;

    float2 z = reinterpret_cast<const float2*>(x)[row];
    float a = z.x;
    float b = z.y;

    for (int l = 0; l < NL; ++l) {
        const float* __restrict__ w1 = W1 + l * HID;
        const float* __restrict__ c1 = b1 + l * HID;
        const float* __restrict__ w2 = W2 + l * HID * HID;
        const float* __restrict__ c2 = b2 + l * HID;
        const float* __restrict__ w3 = W3 + l * 2 * HID;
        const float* __restrict__ c3 = b3 + l * 2;

        float h1[HID];
        #pragma unroll
        for (int k = 0; k < HID; ++k) {
            float v = fmaxf(fmaf(a, w1[k], c1[k]), 0.0f);
            asm volatile("" : "+v"(v));
            h1[k] = v;
        }

        float o0 = c3[0];
        float o1 = c3[1];

        #pragma unroll 2
        for (int j = 0; j < HID; ++j) {
            const float* __restrict__ w2row = w2 + j * HID;
            float acc0 = c2[j];
            float acc1 = 0.0f;
            #pragma unroll
            for (int k = 0; k < HID; k += 2) {
                acc0 = fmaf(h1[k],     w2row[k],     acc0);
                acc1 = fmaf(h1[k + 1], w2row[k + 1], acc1);
            }
            float h = fmaxf(acc0 + acc1, 0.0f);
            o0 = fmaf(h, w3[j], o0);
            o1 = fmaf(h, w3[HID + j], o1);
        }

        float nb = fmaf(b, __expf(o1), o0);
        b = a;
        a = nb;
    }

    reinterpret_cast<float2*>(out)[row] = make_float2(a, b);
}

extern "C" void kernel_launch(void* const* d_in, const int* in_sizes, int n_in,
                              void* d_out, int out_size, void* d_ws, size_t ws_size,
                              hipStream_t stream)
{
    const float* x  = (const float*)d_in[0];
    const float* W1 = (const float*)d_in[1];
    const float* b1 = (const float*)d_in[2];
    const float* W2 = (const float*)d_in[3];
    const float* b2 = (const float*)d_in[4];
    const float* W3 = (const float*)d_in[5];
    const float* b3 = (const float*)d_in[6];
    float* out = (float*)d_out;

    int nrows = in_sizes[0] / 2;

    if (ws_size >= TAB_BYTES) {
        uint2* tab = (uint2*)d_ws;
        dim3 bgrid(NCELLS / BN, NL);
        build_cells_kernel<<<bgrid, 320, 0, stream>>>(W1, b1, W2, b2, W3, b3, tab);
        int grid = (nrows + ROWS_PER_BLOCK - 1) / ROWS_PER_BLOCK;
        flow_lds_kernel<<<grid, TPB, 0, stream>>>(x, tab, out, nrows);
    } else {
        int grid = (nrows + 255) / 256;
        flow_fp32_kernel<<<grid, 256, 0, stream>>>(x, W1, b1, W2, b2, W3, b3, out, nrows);
    }
}

// Round 10
// 57.035 us; speedup vs baseline: 1.5687x; 1.5261x over previous
//
#include <hip/hip_runtime.h>
#include <hip/hip_bf16.h>
#include <string.h>

#define NL 32
#define HID 64

// Piecewise-linear f32 cell table over z1 in [-16, 16], 1024 cells (1/32).
// ReLU MLP on a scalar is exactly piecewise-linear; lerp + edge extrapolation
// validated rounds 1-8 (f32-lerp absmax flat at 0.016-0.031 for widths
// 1/512..1/64 -> kink-dominated, insensitive to width). Cell: float4
// (shift, scale=exp(ls), dshift, dscale) = 16 B, single ds_read_b128 gather,
// f32 lerp (3 fmaf -- round 8 showed fp16 lerp triples VALU, don't).
#define NCELLS 1024
#define NNODES (NCELLS + 1)
#define SCALE  32.0f
#define OFFSET 512.0f
#define TAB_BYTES ((size_t)NL * NCELLS * sizeof(float4))   // 512 KB

#define BN  256                      // cells per build block
#define TPB 512                      // 8 waves per block
#define RPT 8                        // rows per thread -> 512 blocks = 2/CU
#define ROWS_PER_BLOCK (TPB * RPT)   // 4096
#define CHUNKS (NCELLS / TPB)        // 2 x 16B global_load_lds per thread/layer

// ------------- fused build: eval 257 nodes, write 256 f32 cells ------------
// blockIdx.y = layer -> weight reads wave-uniform (scalar loads).
__global__ __launch_bounds__(320) void build_cells_kernel(
    const float* __restrict__ W1,
    const float* __restrict__ b1,
    const float* __restrict__ W2,
    const float* __restrict__ b2,
    const float* __restrict__ W3,
    const float* __restrict__ b3,
    float4* __restrict__ tab)
{
    const int tid = threadIdx.x;
    const int l = blockIdx.y;
    const int base = blockIdx.x * BN;

    __shared__ float2 nodes[BN + 1];

    if (tid <= BN) {
        int node = base + tid;
        float a = -16.0f + (float)node * (1.0f / 32.0f);   // exact in fp32

        const float* __restrict__ w1 = W1 + l * HID;
        const float* __restrict__ c1 = b1 + l * HID;
        const float* __restrict__ w2 = W2 + l * HID * HID;
        const float* __restrict__ c2 = b2 + l * HID;
        const float* __restrict__ w3 = W3 + l * 2 * HID;
        const float* __restrict__ c3 = b3 + l * 2;

        float h1[HID];
        #pragma unroll
        for (int k = 0; k < HID; ++k) {
            float v = fmaxf(fmaf(a, w1[k], c1[k]), 0.0f);
            asm volatile("" : "+v"(v));   // pin in VGPR; block remat
            h1[k] = v;
        }

        float o0 = c3[0];
        float o1 = c3[1];

        #pragma unroll 2
        for (int j = 0; j < HID; ++j) {
            const float* __restrict__ w2row = w2 + j * HID;
            float acc0 = c2[j];
            float acc1 = 0.0f;
            #pragma unroll
            for (int k = 0; k < HID; k += 2) {
                acc0 = fmaf(h1[k],     w2row[k],     acc0);
                acc1 = fmaf(h1[k + 1], w2row[k + 1], acc1);
            }
            float h = fmaxf(acc0 + acc1, 0.0f);
            o0 = fmaf(h, w3[j], o0);
            o1 = fmaf(h, w3[HID + j], o1);
        }

        nodes[tid] = make_float2(o0, expf(o1));  // (shift, scale)
    }
    __syncthreads();

    if (tid < BN) {
        float2 v0 = nodes[tid];
        float2 v1 = nodes[tid + 1];
        tab[(size_t)l * NCELLS + base + tid] =
            make_float4(v0.x, v0.y, v1.x - v0.x, v1.y - v0.y);
    }
}

// ---------------- helpers ---------------------------------------------------
__device__ __forceinline__ float2 nt_load_f2(const float* p) {
    unsigned long long raw =
        __builtin_nontemporal_load((const unsigned long long*)p);
    float2 v;
    memcpy(&v, &raw, 8);
    return v;
}
__device__ __forceinline__ void nt_store_f2(float* p, float2 v) {
    unsigned long long raw;
    memcpy(&raw, &v, 8);
    __builtin_nontemporal_store(raw, (unsigned long long*)p);
}

// async global->LDS DMA, 16 B per lane. LDS dest must be wave-uniform base;
// lane i lands at base + i*16. Our staging is linear in lane order -> legal.
__device__ __forceinline__ void gl2lds16(const float4* g, float4* l) {
    __builtin_amdgcn_global_load_lds(
        (const __attribute__((address_space(1))) void*)g,
        (__attribute__((address_space(3))) void*)l,
        16, 0, 0);
}

// ---------------- main pass: f32 LDS cell table, DMA staging ---------------
// Round-6 structure (50 us, LDS-bound): RPT=8, 2 blocks/CU, one barrier per
// layer. Staging now via global_load_lds: no register round trip, no VALU
// ds_write, cannot be sunk by the compiler (round-7 pathology). The
// __syncthreads() at end of layer drains vmcnt(0) -> next buffer ready.
__global__ __launch_bounds__(TPB) void flow_lds_kernel(
    const float* __restrict__ x,
    const float4* __restrict__ tabg,
    float* __restrict__ out,
    int nrows)
{
    __shared__ float4 buf[2][NCELLS];   // 2 x 16 KiB

    const int tid = threadIdx.x;
    const int wbase = tid & ~63;        // wave-uniform lane-0 index
    const size_t rbase = (size_t)blockIdx.x * ROWS_PER_BLOCK;

    float a[RPT], b[RPT];
    #pragma unroll
    for (int i = 0; i < RPT; ++i) {
        size_t r = rbase + (size_t)i * TPB + tid;
        float2 z = (r < (size_t)nrows) ? nt_load_f2(x + 2 * r)
                                       : make_float2(0.f, 0.f);
        a[i] = z.x;
        b[i] = z.y;
    }

    // stage layer 0 into buf[0] (DMA); __syncthreads drains vmcnt
    #pragma unroll
    for (int c = 0; c < CHUNKS; ++c)
        gl2lds16(tabg + c * TPB + tid, &buf[0][c * TPB + wbase]);
    __syncthreads();

    int cur = 0;
    for (int l = 0; l < NL; ++l) {
        // issue next-layer DMA into the other half (in flight during gather)
        if (l + 1 < NL) {
            const float4* __restrict__ src = tabg + (size_t)(l + 1) * NCELLS;
            #pragma unroll
            for (int c = 0; c < CHUNKS; ++c)
                gl2lds16(src + c * TPB + tid, &buf[cur ^ 1][c * TPB + wbase]);
        }

        // gather-compute current layer from buf[cur] (f32 lerp, 3 fmaf)
        #pragma unroll
        for (int i = 0; i < RPT; ++i) {
            float t = fmaf(a[i], SCALE, OFFSET);
            int idx = (int)t;
            idx = idx < 0 ? 0 : (idx > NCELLS - 1 ? NCELLS - 1 : idx);
            float f = t - (float)idx;            // out-of-range -> extrapolate
            float4 nd = buf[cur][idx];
            float sh = fmaf(f, nd.z, nd.x);
            float sc = fmaf(f, nd.w, nd.y);
            float nb = fmaf(b[i], sc, sh);
            b[i] = a[i];
            a[i] = nb;
        }

        __syncthreads();   // waits vmcnt(0) + lgkmcnt(0), then barrier
        cur ^= 1;
    }

    #pragma unroll
    for (int i = 0; i < RPT; ++i) {
        size_t r = rbase + (size_t)i * TPB + tid;
        if (r < (size_t)nrows)
            nt_store_f2(out + 2 * r, make_float2(a[i], b[i]));
    }
}

// ---------------- fallback: direct fp32 (ws too small) ---------------------
__global__ __launch_bounds__(256, 2) void flow_fp32_kernel(
    const float* __restrict__ x,
    const float* __restrict__ W1,
    const float* __restrict__ b1,
    const float* __restrict__ W2,
    const float* __restrict__ b2,
    const float* __restrict__ W3,
    const float* __restrict__ b3,
    float* __restrict__ out,
    int nrows)
{
    int row = blockIdx.x * blockDim.x + threadIdx.x;
    if (row >= nrows) return;

    float2 z = reinterpret_cast<const float2*>(x)[row];
    float a = z.x;
    float b = z.y;

    for (int l = 0; l < NL; ++l) {
        const float* __restrict__ w1 = W1 + l * HID;
        const float* __restrict__ c1 = b1 + l * HID;
        const float* __restrict__ w2 = W2 + l * HID * HID;
        const float* __restrict__ c2 = b2 + l * HID;
        const float* __restrict__ w3 = W3 + l * 2 * HID;
        const float* __restrict__ c3 = b3 + l * 2;

        float h1[HID];
        #pragma unroll
        for (int k = 0; k < HID; ++k) {
            float v = fmaxf(fmaf(a, w1[k], c1[k]), 0.0f);
            asm volatile("" : "+v"(v));
            h1[k] = v;
        }

        float o0 = c3[0];
        float o1 = c3[1];

        #pragma unroll 2
        for (int j = 0; j < HID; ++j) {
            const float* __restrict__ w2row = w2 + j * HID;
            float acc0 = c2[j];
            float acc1 = 0.0f;
            #pragma unroll
            for (int k = 0; k < HID; k += 2) {
                acc0 = fmaf(h1[k],     w2row[k],     acc0);
                acc1 = fmaf(h1[k + 1], w2row[k + 1], acc1);
            }
            float h = fmaxf(acc0 + acc1, 0.0f);
            o0 = fmaf(h, w3[j], o0);
            o1 = fmaf(h, w3[HID + j], o1);
        }

        float nb = fmaf(b, __expf(o1), o0);
        b = a;
        a = nb;
    }

    reinterpret_cast<float2*>(out)[row] = make_float2(a, b);
}

extern "C" void kernel_launch(void* const* d_in, const int* in_sizes, int n_in,
                              void* d_out, int out_size, void* d_ws, size_t ws_size,
                              hipStream_t stream)
{
    const float* x  = (const float*)d_in[0];
    const float* W1 = (const float*)d_in[1];
    const float* b1 = (const float*)d_in[2];
    const float* W2 = (const float*)d_in[3];
    const float* b2 = (const float*)d_in[4];
    const float* W3 = (const float*)d_in[5];
    const float* b3 = (const float*)d_in[6];
    float* out = (float*)d_out;

    int nrows = in_sizes[0] / 2;

    if (ws_size >= TAB_BYTES) {
        float4* tab = (float4*)d_ws;
        dim3 bgrid(NCELLS / BN, NL);
        build_cells_kernel<<<bgrid, 320, 0, stream>>>(W1, b1, W2, b2, W3, b3, tab);
        int grid = (nrows + ROWS_PER_BLOCK - 1) / ROWS_PER_BLOCK;
        flow_lds_kernel<<<grid, TPB, 0, stream>>>(x, tab, out, nrows);
    } else {
        int grid = (nrows + 255) / 256;
        flow_fp32_kernel<<<grid, 256, 0, stream>>>(x, W1, b1, W2, b2, W3, b3, out, nrows);
    }
}